// Round 7
// baseline (185.820 us; speedup 1.0000x reference)
//
#include <hip/hip_runtime.h>
#include <cstddef>
#include <cstdint>

#define EPSBN 1e-5f
constexpr int B_ = 4, N_ = 2048, K_ = 20;

typedef __attribute__((ext_vector_type(8))) _Float16 half8v;
typedef __attribute__((ext_vector_type(4))) float f32x4;
typedef const __attribute__((address_space(1))) unsigned int* gas_t;
typedef __attribute__((address_space(3))) unsigned int* las_t;

// batch-XCD swizzle: block B -> (batch, local) with B&7 = XCD slot, batch b on slots {2b,2b+1}
__device__ __forceinline__ void swz_batch(int B, int& b, int& local) {
    b = (B & 7) >> 1;
    local = ((B >> 3) << 1) | (B & 1);
}

// ---------------- fused weight prep (layers 1-3 conv + w4 cast) ----------------

__device__ __forceinline__ void prep_conv(const float* __restrict__ W, _Float16* __restrict__ W2h,
                                          int O, int C, int i) {
    int o = i / C, c = i - o * C;
    float a = W[o * 2 * C + c];
    float d = W[o * 2 * C + C + c] - a;
    W2h[(size_t)o * C + c] = (_Float16)a;
    W2h[(size_t)(O + o) * C + c] = (_Float16)d;
}

__global__ void k_prep_all(const float* __restrict__ w1, const float* __restrict__ w2,
                           const float* __restrict__ w3, const float* __restrict__ w4,
                           _Float16* __restrict__ W2h1, _Float16* __restrict__ W2h2,
                           _Float16* __restrict__ W2h3, _Float16* __restrict__ w4h) {
    int i = blockIdx.x * 256 + threadIdx.x;
    if (i < 8192) { prep_conv(w1, W2h1, 128, 64, i); return; }
    i -= 8192;
    if (i < 32768) { prep_conv(w2, W2h2, 256, 128, i); return; }
    i -= 32768;
    if (i < 131072) { prep_conv(w3, W2h3, 512, 256, i); return; }
    i -= 131072;
    if (i < 983040) w4h[i] = (_Float16)w4[i];
}

// ---------------- MFMA GEMM with fused BN+lrelu on the A operand ----------------
// out(fp16) = lrelu(scale*Apre + shift) @ Bw^T.  A is read from up to 4 per-layer
// pre-BN extremum buffers (K-tile c0 selects source via thresholds; boundaries are
// multiples of the 64-wide K-step).  A: global dwordx4 -> f32 affine+lrelu -> fp16
// -> ds_write_b128.  IMPORTANT (round-6 NaN lesson): global_load_lds scatters to
// uniform_base + lane*16B implicitly; the explicit ds_write must add "+ lane" itself.
// B (weights): global_load_lds direct.  128x128 tile, 4 waves x (64x64),
// single-buffer (r4/r5: pipelining neutral here).  32KB LDS, 3 blocks/CU.
// Deletes the k_bn_apply kernels and the cath round-trip; affine VALU rides in
// the ~90% MFMA-idle stall cycles.
template<bool STATS>
__global__ __launch_bounds__(256, 3)
void k_gemm(const _Float16* __restrict__ A0, const _Float16* __restrict__ A1,
            const _Float16* __restrict__ A2, const _Float16* __restrict__ A3,
            int t1, int t2, int t3,              // c0 thresholds for source select
            int c1, int c2, int c3,              // coffs  (coff0 = 0)
            int s0, int s1, int s2, int s3,      // row strides of the sources
            const float* __restrict__ scale, const float* __restrict__ shift, // idx by c0+col
            const _Float16* __restrict__ Bw, int K,
            _Float16* __restrict__ outp, int so,
            float* __restrict__ psum, float* __restrict__ psq) {
    __shared__ __align__(16) _Float16 Als[128 * 64];
    __shared__ __align__(16) _Float16 Bls[128 * 64];
    const int tid = threadIdx.x, lane = tid & 63, w = tid >> 6;
    int bsw, lsw;
    swz_batch(blockIdx.x, bsw, lsw);                 // lsw in [0,16)
    const int m0 = (bsw * 16 + lsw) * 128;
    const int n0 = blockIdx.y * 128;
    const int wr = (w >> 1) * 64, wc = (w & 1) * 64;

    f32x4 acc[4][4];
#pragma unroll
    for (int i = 0; i < 4; ++i)
#pragma unroll
        for (int j = 0; j < 4; ++j) acc[i][j] = (f32x4){0.f, 0.f, 0.f, 0.f};

    int srow[4], scol[4];
#pragma unroll
    for (int j = 0; j < 4; ++j) {
        int idx = w * 256 + j * 64 + lane;
        srow[j] = idx >> 3;
        scol[j] = ((idx & 7) ^ (srow[j] & 7)) * 8;
    }
    int aoff[4][2], boff[4][2];
#pragma unroll
    for (int i = 0; i < 4; ++i) {
        int ra = wr + i * 16 + (lane & 15);
        int rb = wc + i * 16 + (lane & 15);
#pragma unroll
        for (int t = 0; t < 2; ++t) {
            aoff[i][t] = ra * 64 + ((((lane >> 4) + t * 4) ^ (ra & 7)) * 8);
            boff[i][t] = rb * 64 + ((((lane >> 4) + t * 4) ^ (rb & 7)) * 8);
        }
    }

    for (int c0 = 0; c0 < K; c0 += 64) {
        // ---- wave-uniform source select for this K-tile ----
        const _Float16* src; int stride, coff;
        if (c0 < t1)      { src = A0; stride = s0; coff = 0;  }
        else if (c0 < t2) { src = A1; stride = s1; coff = c1; }
        else if (c0 < t3) { src = A2; stride = s2; coff = c2; }
        else              { src = A3; stride = s3; coff = c3; }

        // B: direct global->LDS (no transform needed on weights)
#pragma unroll
        for (int j = 0; j < 4; ++j) {
            const _Float16* gb = &Bw[(size_t)(n0 + srow[j]) * K + c0 + scol[j]];
            __builtin_amdgcn_global_load_lds((gas_t)(const void*)gb,
                                             (las_t)(void*)&Bls[(w * 256 + j * 64) * 8], 16, 0, 0);
        }
        // A: reg-stage all 4 chunks (loads pipelined), then transform + LDS write
        half8v av[4];
#pragma unroll
        for (int j = 0; j < 4; ++j)
            av[j] = *(const half8v*)&src[(size_t)(m0 + srow[j]) * stride + (c0 - coff) + scol[j]];
#pragma unroll
        for (int j = 0; j < 4; ++j) {
            const int cb = c0 + scol[j];
            float4 sc0 = *(const float4*)&scale[cb];
            float4 sc1 = *(const float4*)&scale[cb + 4];
            float4 sh0 = *(const float4*)&shift[cb];
            float4 sh1 = *(const float4*)&shift[cb + 4];
            half8v r;
            float y;
            y = sc0.x * (float)av[j][0] + sh0.x; r[0] = (_Float16)fmaxf(y, 0.2f * y);
            y = sc0.y * (float)av[j][1] + sh0.y; r[1] = (_Float16)fmaxf(y, 0.2f * y);
            y = sc0.z * (float)av[j][2] + sh0.z; r[2] = (_Float16)fmaxf(y, 0.2f * y);
            y = sc0.w * (float)av[j][3] + sh0.w; r[3] = (_Float16)fmaxf(y, 0.2f * y);
            y = sc1.x * (float)av[j][4] + sh1.x; r[4] = (_Float16)fmaxf(y, 0.2f * y);
            y = sc1.y * (float)av[j][5] + sh1.y; r[5] = (_Float16)fmaxf(y, 0.2f * y);
            y = sc1.z * (float)av[j][6] + sh1.z; r[6] = (_Float16)fmaxf(y, 0.2f * y);
            y = sc1.w * (float)av[j][7] + sh1.w; r[7] = (_Float16)fmaxf(y, 0.2f * y);
            *(half8v*)&Als[(w * 256 + j * 64 + lane) * 8] = r;   // + lane: explicit per-lane slot
        }
        __syncthreads();     // drains vmcnt (B lds-loads) + lgkm (A ds_writes)
#pragma unroll
        for (int t = 0; t < 2; ++t) {
            half8v a[4], b[4];
#pragma unroll
            for (int i = 0; i < 4; ++i) {
                a[i] = *(const half8v*)&Als[aoff[i][t]];
                b[i] = *(const half8v*)&Bls[boff[i][t]];
            }
#pragma unroll
            for (int i = 0; i < 4; ++i)
#pragma unroll
                for (int j = 0; j < 4; ++j)
                    acc[i][j] = __builtin_amdgcn_mfma_f32_16x16x32_f16(a[i], b[j], acc[i][j], 0, 0, 0);
        }
        __syncthreads();     // LDS reuse protection for next iteration
    }
#pragma unroll
    for (int i = 0; i < 4; ++i)
#pragma unroll
        for (int j = 0; j < 4; ++j)
#pragma unroll
            for (int e = 0; e < 4; ++e) {
                int row = m0 + wr + i * 16 + (lane >> 4) * 4 + e;
                int col = n0 + wc + j * 16 + (lane & 15);
                outp[(size_t)row * so + col] = (_Float16)acc[i][j][e];
            }
    if constexpr (STATS) {
        int slice = blockIdx.x & 63;
#pragma unroll
        for (int j = 0; j < 4; ++j) {
            float s = 0.f, q = 0.f;
#pragma unroll
            for (int i = 0; i < 4; ++i)
#pragma unroll
                for (int e = 0; e < 4; ++e) {
                    float v = acc[i][j][e];
                    s += v; q += v * v;
                }
            s += __shfl_xor(s, 16); s += __shfl_xor(s, 32);
            q += __shfl_xor(q, 16); q += __shfl_xor(q, 32);
            if ((lane >> 4) == 0) {
                int col = n0 + wc + j * 16 + lane;
                atomicAdd(&psum[slice * 1024 + col], s);
                atomicAdd(&psq[slice * 1024 + col], q);
            }
        }
    }
}

// ---------------- layer-0: fused dense (C=3) + gather-reduce + BN stats ----------------
__global__ __launch_bounds__(256)
void k_gather0(const float* __restrict__ x, const float* __restrict__ w0,
               const int* __restrict__ nidx, const float* __restrict__ g,
               _Float16* __restrict__ exth,
               float* __restrict__ psum, float* __restrict__ psq) {
    constexpr int O = 64, VPT = 8, P = 32;
    __shared__ float s_red[P * O];
    __shared__ float q_red[P * O];
    const int tid = threadIdx.x;
    const int pl = tid / VPT, v = tid % VPT;
    int bsw, local;
    swz_batch(blockIdx.x, bsw, local);               // grid 256: local in [0,32)
    const int bbase = bsw * N_;
    const int p = bbase + local * P + pl;
    float wa[8][3], wd[8][3], sg[8];
#pragma unroll
    for (int e = 0; e < 8; ++e) {
        int o = v * 8 + e;
        float a0 = w0[o * 6], a1 = w0[o * 6 + 1], a2 = w0[o * 6 + 2];
        wa[e][0] = a0; wa[e][1] = a1; wa[e][2] = a2;
        wd[e][0] = w0[o * 6 + 3] - a0;
        wd[e][1] = w0[o * 6 + 4] - a1;
        wd[e][2] = w0[o * 6 + 5] - a2;
        sg[e] = (g[o] >= 0.f) ? 1.f : -1.f;
    }
    float mx[8], sm[8], sq[8];
#pragma unroll
    for (int e = 0; e < 8; ++e) { mx[e] = -3.4e38f; sm[e] = 0.f; sq[e] = 0.f; }
    const int* np = nidx + p * K_;
#pragma unroll 4
    for (int k = 0; k < K_; ++k) {
        int j = bbase + np[k];
        float x0 = x[j * 3], x1 = x[j * 3 + 1], x2 = x[j * 3 + 2];
#pragma unroll
        for (int e = 0; e < 8; ++e) {
            float f = wa[e][0] * x0 + wa[e][1] * x1 + wa[e][2] * x2;
            mx[e] = fmaxf(mx[e], f * sg[e]);
            sm[e] += f;
            sq[e] += f * f;
        }
    }
    float xp0 = x[p * 3], xp1 = x[p * 3 + 1], xp2 = x[p * 3 + 2];
    const float Kf = (float)K_;
    half8v exo;
#pragma unroll
    for (int e = 0; e < 8; ++e) {
        float zf = wd[e][0] * xp0 + wd[e][1] * xp1 + wd[e][2] * xp2;
        exo[e] = (_Float16)(sg[e] * mx[e] + zf);
        s_red[pl * O + v * 8 + e] = sm[e] + Kf * zf;
        q_red[pl * O + v * 8 + e] = sq[e] + 2.f * zf * sm[e] + Kf * zf * zf;
    }
    *(half8v*)&exth[(size_t)p * O + v * 8] = exo;
    __syncthreads();
    int slice = blockIdx.x & 63;
    for (int ch = tid; ch < O; ch += 256) {
        float s = 0.f, q = 0.f;
#pragma unroll
        for (int pp = 0; pp < P; ++pp) { s += s_red[pp * O + ch]; q += q_red[pp * O + ch]; }
        atomicAdd(&psum[slice * 1024 + ch], s);
        atomicAdd(&psq[slice * 1024 + ch], q);
    }
}

// ---------------- gather-reduce + fused BN stats (single extremum, batch-XCD-swizzled) ----------------
template<int O>
__global__ __launch_bounds__(256)
void k_gather(const _Float16* __restrict__ Z, const int* __restrict__ nidx,
              const float* __restrict__ g,
              _Float16* __restrict__ exth,
              float* __restrict__ psum, float* __restrict__ psq) {
    constexpr int VPT = O / 8, P = 256 / VPT;
    __shared__ float s_red[P * O];
    __shared__ float q_red[P * O];
    const int tid = threadIdx.x;
    const int pl = tid / VPT, v = tid % VPT;
    int bsw, local;
    swz_batch(blockIdx.x, bsw, local);               // local in [0, 2048/P)
    const int bbase = bsw * N_;
    const int p = bbase + local * P + pl;
    float sg[8];
#pragma unroll
    for (int e = 0; e < 8; ++e) sg[e] = (g[v * 8 + e] >= 0.f) ? 1.f : -1.f;
    float mx[8], sm[8], sq[8];
#pragma unroll
    for (int e = 0; e < 8; ++e) { mx[e] = -3.4e38f; sm[e] = 0.f; sq[e] = 0.f; }
    const int* np = nidx + p * K_;
#pragma unroll 4
    for (int k = 0; k < K_; ++k) {
        int j = np[k];
        half8v z = *(const half8v*)&Z[(size_t)(bbase + j) * (2 * O) + v * 8];
#pragma unroll
        for (int e = 0; e < 8; ++e) {
            float f = (float)z[e];
            mx[e] = fmaxf(mx[e], f * sg[e]);
            sm[e] += f;
            sq[e] += f * f;
        }
    }
    half8v zd = *(const half8v*)&Z[(size_t)p * (2 * O) + O + v * 8];
    const float Kf = (float)K_;
    half8v exo;
#pragma unroll
    for (int e = 0; e < 8; ++e) {
        float zf = (float)zd[e];
        exo[e] = (_Float16)(sg[e] * mx[e] + zf);
        s_red[pl * O + v * 8 + e] = sm[e] + Kf * zf;
        q_red[pl * O + v * 8 + e] = sq[e] + 2.f * zf * sm[e] + Kf * zf * zf;
    }
    *(half8v*)&exth[(size_t)p * O + v * 8] = exo;
    __syncthreads();
    int slice = blockIdx.x & 63;
    for (int ch = tid; ch < O; ch += 256) {
        float s = 0.f, q = 0.f;
#pragma unroll
        for (int pp = 0; pp < P; ++pp) { s += s_red[pp * O + ch]; q += q_red[pp * O + ch]; }
        atomicAdd(&psum[slice * 1024 + ch], s);
        atomicAdd(&psq[slice * 1024 + ch], q);
    }
}

// ---------------- finalize: sum 64 slices -> scale/shift ----------------
__global__ void k_finalize_sl(const float* __restrict__ psum, const float* __restrict__ psq,
                              const float* __restrict__ g, const float* __restrict__ b,
                              float cntInv, int O,
                              float* __restrict__ scale, float* __restrict__ shift) {
    int o = blockIdx.x * 256 + threadIdx.x;
    if (o >= O) return;
    float s = 0.f, q = 0.f;
    for (int i = 0; i < 64; ++i) { s += psum[i * 1024 + o]; q += psq[i * 1024 + o]; }
    float m = s * cntInv;
    float v = q * cntInv - m * m;
    float sc = g[o] * rsqrtf(fmaxf(v, 0.f) + EPSBN);
    scale[o] = sc;
    shift[o] = b[o] - m * sc;
}

// BN+lrelu on Y4 (B,N,1024 fp16), transposed store -> fo (B,1024,N f32), fused pool partials
__global__ void k_feats_out(const _Float16* __restrict__ Y4, const float* __restrict__ scale,
                            const float* __restrict__ shift, float* __restrict__ fo,
                            float* __restrict__ pmax, float* __restrict__ psumn) {
    __shared__ float tile[32][33];
    int tx = threadIdx.x, ty = threadIdx.y;      // (32,8)
    int b = blockIdx.z;
    int n0 = blockIdx.x * 32, c0 = blockIdx.y * 32;
#pragma unroll
    for (int i = 0; i < 4; ++i) {
        int n = n0 + ty + i * 8;
        int c = c0 + tx;
        float v = (float)Y4[((size_t)(b * N_ + n)) * 1024 + c];
        v = scale[c] * v + shift[c];
        v = v > 0.f ? v : 0.2f * v;
        tile[ty + i * 8][tx] = v;
    }
    __syncthreads();
#pragma unroll
    for (int i = 0; i < 4; ++i) {
        int c = c0 + ty + i * 8;
        int n = n0 + tx;
        float v2 = tile[tx][ty + i * 8];
        fo[((size_t)(b * 1024 + c)) * N_ + n] = v2;
        float mx = v2, s = v2;
#pragma unroll
        for (int d = 1; d < 32; d <<= 1) {
            mx = fmaxf(mx, __shfl_xor(mx, d));
            s += __shfl_xor(s, d);
        }
        if (tx == 0) {
            int bc = (b << 10) + c;
            pmax[(size_t)bc * 64 + blockIdx.x] = mx;
            psumn[(size_t)bc * 64 + blockIdx.x] = s;
        }
    }
}

// final pool: per (b,c) reduce 64 tile-partials -> z0 (B,2048) = [max | mean]
__global__ void k_pool2(const float* __restrict__ pmax, const float* __restrict__ psumn,
                        float* __restrict__ z0) {
    int bc = blockIdx.x * 4 + (threadIdx.x >> 6);
    int lane = threadIdx.x & 63;
    float mx = pmax[(size_t)bc * 64 + lane];
    float s  = psumn[(size_t)bc * 64 + lane];
#pragma unroll
    for (int d = 1; d < 64; d <<= 1) {
        mx = fmaxf(mx, __shfl_xor(mx, d));
        s += __shfl_xor(s, d);
    }
    if (lane == 0) {
        int b = bc >> 10, c = bc & 1023;
        z0[b * 2048 + c] = mx;
        z0[b * 2048 + 1024 + c] = s * (1.f / N_);
    }
}

// ---------------- FC: one wave per (batch, output) dot product; optional fused batch-BN+lrelu ----------------
__global__ void k_fc(const float* __restrict__ zin, const float* __restrict__ W,
                     const float* __restrict__ bias,
                     const float* __restrict__ gg, const float* __restrict__ gb,
                     int C, int O, float* __restrict__ zout) {
    __shared__ float sh4[4];
    const int b = threadIdx.x >> 6;
    const int lane = threadIdx.x & 63;
    const int o = blockIdx.x;
    const float* wr = W + (size_t)o * C;
    const float* zr = zin + b * C;
    float s = 0.f;
    for (int c = lane * 4; c < C; c += 256) {
        const float4 wv = *(const float4*)&wr[c];
        const float4 zv = *(const float4*)&zr[c];
        s += wv.x * zv.x + wv.y * zv.y + wv.z * zv.z + wv.w * zv.w;
    }
    s += __shfl_xor(s, 1);
    s += __shfl_xor(s, 2);
    s += __shfl_xor(s, 4);
    s += __shfl_xor(s, 8);
    s += __shfl_xor(s, 16);
    s += __shfl_xor(s, 32);
    if (!gg) {
        if (lane == 0) zout[b * O + o] = s + (bias ? bias[o] : 0.f);
        return;
    }
    if (lane == 0) sh4[b] = s + (bias ? bias[o] : 0.f);
    __syncthreads();
    if (threadIdx.x == 0) {
        float v0 = sh4[0], v1 = sh4[1], v2 = sh4[2], v3 = sh4[3];
        float m = 0.25f * (v0 + v1 + v2 + v3);
        float d0 = v0 - m, d1 = v1 - m, d2 = v2 - m, d3 = v3 - m;
        float var = 0.25f * (d0 * d0 + d1 * d1 + d2 * d2 + d3 * d3);
        float sc = gg[o] * rsqrtf(var + EPSBN);
        float shv = gb[o];
        float r0 = sc * d0 + shv, r1 = sc * d1 + shv, r2 = sc * d2 + shv, r3 = sc * d3 + shv;
        zout[o]         = r0 > 0.f ? r0 : 0.2f * r0;
        zout[O + o]     = r1 > 0.f ? r1 : 0.2f * r1;
        zout[2 * O + o] = r2 > 0.f ? r2 : 0.2f * r2;
        zout[3 * O + o] = r3 > 0.f ? r3 : 0.2f * r3;
    }
}

// ---------------- launch ----------------

extern "C" void kernel_launch(void* const* d_in, const int* in_sizes, int n_in,
                              void* d_out, int out_size, void* d_ws, size_t ws_size,
                              hipStream_t stream) {
    const float* x    = (const float*)d_in[0];
    const int*   nidx = (const int*)d_in[1];
    const float* w[5]  = {(const float*)d_in[2], (const float*)d_in[5], (const float*)d_in[8],
                          (const float*)d_in[11], (const float*)d_in[14]};
    const float* g[5]  = {(const float*)d_in[3], (const float*)d_in[6], (const float*)d_in[9],
                          (const float*)d_in[12], (const float*)d_in[15]};
    const float* bb[5] = {(const float*)d_in[4], (const float*)d_in[7], (const float*)d_in[10],
                          (const float*)d_in[13], (const float*)d_in[16]};
    const float* lw1 = (const float*)d_in[17];
    const float* g6  = (const float*)d_in[18];
    const float* b6  = (const float*)d_in[19];
    const float* lw2 = (const float*)d_in[20];
    const float* lb2 = (const float*)d_in[21];
    const float* g7  = (const float*)d_in[22];
    const float* b7  = (const float*)d_in[23];
    const float* lw3 = (const float*)d_in[24];
    const float* lb3 = (const float*)d_in[25];

    float* out = (float*)d_out;
    float* fo  = out + 1024;              // feats (B,1024,N)

    uint8_t* base8 = (uint8_t*)d_ws;
    size_t off = 0;
    auto alloc = [&](size_t bytes) -> void* {
        void* r = base8 + off;
        off += (bytes + 255) & ~(size_t)255;
        return r;
    };
    _Float16* Z     = (_Float16*)alloc((size_t)8192 * 1024 * 2);    // 16.8 MB
    _Float16* exth0 = (_Float16*)alloc((size_t)8192 * 64 * 2);      // 1 MB
    _Float16* exth1 = (_Float16*)alloc((size_t)8192 * 128 * 2);     // 2.1 MB
    _Float16* exth2 = (_Float16*)alloc((size_t)8192 * 256 * 2);     // 4.2 MB
    _Float16* exth3 = (_Float16*)alloc((size_t)8192 * 512 * 2);     // 8.4 MB
    _Float16* Y4    = (_Float16*)alloc((size_t)8192 * 1024 * 2);    // 16.8 MB
    _Float16* W2h1  = (_Float16*)alloc((size_t)256 * 64 * 2);
    _Float16* W2h2  = (_Float16*)alloc((size_t)512 * 128 * 2);
    _Float16* W2h3  = (_Float16*)alloc((size_t)1024 * 256 * 2);
    _Float16* w4h   = (_Float16*)alloc((size_t)1024 * 960 * 2);
    float* psumall = (float*)alloc((size_t)5 * 131072 * 4);         // 2.6 MB, 5 regions
    float* pmax  = (float*)alloc((size_t)4096 * 64 * 4);            // 1 MB
    float* psumn = (float*)alloc((size_t)4096 * 64 * 4);            // 1 MB
    float* scaleC = (float*)alloc(960 * 4);    // conv-layer BN scale, cat-channel space
    float* shiftC = (float*)alloc(960 * 4);
    float* scale4 = (float*)alloc(1024 * 4);   // w4-layer BN
    float* shift4 = (float*)alloc(1024 * 4);
    float* z0    = (float*)alloc(8192 * 4);
    float* z1    = (float*)alloc(4096 * 4);
    float* z2    = (float*)alloc(2048 * 4);
    (void)ws_size; (void)in_sizes; (void)n_in; (void)out_size;

    auto psumR = [&](int r) { return psumall + (size_t)r * 131072; };
    auto psqR  = [&](int r) { return psumall + (size_t)r * 131072 + 65536; };
    const int HUGE_T = 1 << 30;

    // one upfront zero of all stat regions + one fused weight-prep launch
    hipMemsetAsync(psumall, 0, (size_t)5 * 131072 * 4, stream);
    k_prep_all<<<(8192 + 32768 + 131072 + 983040 + 255) / 256, 256, 0, stream>>>(
        w[1], w[2], w[3], w[4], W2h1, W2h2, W2h3, w4h);

    // ---- layer 0 (C=3 -> O=64): fused dense + gather; BN applied by consumer GEMMs ----
    k_gather0<<<256, 256, 0, stream>>>(x, w[0], nidx, g[0], exth0, psumR(0), psqR(0));
    k_finalize_sl<<<1, 256, 0, stream>>>(psumR(0), psqR(0), g[0], bb[0], 1.f / (B_ * N_ * K_),
                                         64, scaleC + 0, shiftC + 0);

    // ---- G1: Z = lrelu(bn(exth0)) @ W2h1^T   (M=8192, N=256, K=64) ----
    k_gemm<false><<<dim3(64, 2), 256, 0, stream>>>(
        exth0, exth0, exth0, exth0, HUGE_T, HUGE_T, HUGE_T, 0, 0, 0, 64, 64, 64, 64,
        scaleC + 0, shiftC + 0, W2h1, 64, Z, 256, nullptr, nullptr);
    k_gather<128><<<512, 256, 0, stream>>>(Z, nidx, g[1], exth1, psumR(1), psqR(1));
    k_finalize_sl<<<1, 256, 0, stream>>>(psumR(1), psqR(1), g[1], bb[1], 1.f / (B_ * N_ * K_),
                                         128, scaleC + 64, shiftC + 64);

    // ---- G2: (M=8192, N=512, K=128) ----
    k_gemm<false><<<dim3(64, 4), 256, 0, stream>>>(
        exth1, exth1, exth1, exth1, HUGE_T, HUGE_T, HUGE_T, 0, 0, 0, 128, 128, 128, 128,
        scaleC + 64, shiftC + 64, W2h2, 128, Z, 512, nullptr, nullptr);
    k_gather<256><<<1024, 256, 0, stream>>>(Z, nidx, g[2], exth2, psumR(2), psqR(2));
    k_finalize_sl<<<1, 256, 0, stream>>>(psumR(2), psqR(2), g[2], bb[2], 1.f / (B_ * N_ * K_),
                                         256, scaleC + 192, shiftC + 192);

    // ---- G3: (M=8192, N=1024, K=256) ----
    k_gemm<false><<<dim3(64, 8), 256, 0, stream>>>(
        exth2, exth2, exth2, exth2, HUGE_T, HUGE_T, HUGE_T, 0, 0, 0, 256, 256, 256, 256,
        scaleC + 192, shiftC + 192, W2h3, 256, Z, 1024, nullptr, nullptr);
    k_gather<512><<<2048, 256, 0, stream>>>(Z, nidx, g[3], exth3, psumR(3), psqR(3));
    k_finalize_sl<<<2, 256, 0, stream>>>(psumR(3), psqR(3), g[3], bb[3], 1.f / (B_ * N_ * K_),
                                         512, scaleC + 448, shiftC + 448);

    // ---- G4: Y4 = lrelu(bn(cat)) @ w4^T, cat assembled on the fly from exth0..3 ----
    k_gemm<true><<<dim3(64, 8), 256, 0, stream>>>(
        exth0, exth1, exth2, exth3, 64, 192, 448, 64, 192, 448, 64, 128, 256, 512,
        scaleC, shiftC, w4h, 960, Y4, 1024, psumR(4), psqR(4));
    k_finalize_sl<<<4, 256, 0, stream>>>(psumR(4), psqR(4), g[4], bb[4], 1.f / (B_ * N_), 1024,
                                         scale4, shift4);
    k_feats_out<<<dim3(64, 32, 4), dim3(32, 8), 0, stream>>>(Y4, scale4, shift4, fo, pmax, psumn);
    k_pool2<<<1024, 256, 0, stream>>>(pmax, psumn, z0);

    // ---- FC head (BN fused into FC blocks) ----
    k_fc<<<1024, 256, 0, stream>>>(z0, lw1, nullptr, g6, b6, 2048, 1024, z1);
    k_fc<<<512, 256, 0, stream>>>(z1, lw2, lb2, g7, b7, 1024, 512, z2);
    k_fc<<<256, 256, 0, stream>>>(z2, lw3, lb3, nullptr, nullptr, 512, 256, out);
}

// Round 8
// 168.938 us; speedup vs baseline: 1.0999x; 1.0999x over previous
//
#include <hip/hip_runtime.h>
#include <cstddef>
#include <cstdint>

#define EPSBN 1e-5f
constexpr int B_ = 4, N_ = 2048, K_ = 20;

typedef __attribute__((ext_vector_type(8))) _Float16 half8v;
typedef __attribute__((ext_vector_type(4))) float f32x4;
typedef const __attribute__((address_space(1))) unsigned int* gas_t;
typedef __attribute__((address_space(3))) unsigned int* las_t;

// batch-XCD swizzle: block B -> (batch, local) with B&7 = XCD slot, batch b on slots {2b,2b+1}
__device__ __forceinline__ void swz_batch(int B, int& b, int& local) {
    b = (B & 7) >> 1;
    local = ((B >> 3) << 1) | (B & 1);
}

// ---------------- fused weight prep (layers 1-3 conv + w4 cast) ----------------

__device__ __forceinline__ void prep_conv(const float* __restrict__ W, _Float16* __restrict__ W2h,
                                          int O, int C, int i) {
    int o = i / C, c = i - o * C;
    float a = W[o * 2 * C + c];
    float d = W[o * 2 * C + C + c] - a;
    W2h[(size_t)o * C + c] = (_Float16)a;
    W2h[(size_t)(O + o) * C + c] = (_Float16)d;
}

__global__ void k_prep_all(const float* __restrict__ w1, const float* __restrict__ w2,
                           const float* __restrict__ w3, const float* __restrict__ w4,
                           _Float16* __restrict__ W2h1, _Float16* __restrict__ W2h2,
                           _Float16* __restrict__ W2h3, _Float16* __restrict__ w4h) {
    int i = blockIdx.x * 256 + threadIdx.x;
    if (i < 8192) { prep_conv(w1, W2h1, 128, 64, i); return; }
    i -= 8192;
    if (i < 32768) { prep_conv(w2, W2h2, 256, 128, i); return; }
    i -= 32768;
    if (i < 131072) { prep_conv(w3, W2h3, 512, 256, i); return; }
    i -= 131072;
    if (i < 983040) w4h[i] = (_Float16)w4[i];
}

// ---------------- generic MFMA GEMM: out(fp16) = A (8192 x K, stride sa) @ Bw^T ----------------
// BM x 128 tile (BM=128 default; BM=64 for small-N G1 to double CU coverage).
// 4 waves x ((BM/2) x 64), global_load_lds staging with XOR-swizzled LDS, single-buffer
// (r4/r5/r7: pipelining & in-GEMM transforms all neutral-to-negative here).
// 3 blocks/CU headroom for cross-block latency hiding (m114).
template<bool STATS, int BM>
__global__ __launch_bounds__(256, 3)
void k_gemm(const _Float16* __restrict__ A, int sa,
            const _Float16* __restrict__ Bw, int K,
            _Float16* __restrict__ outp, int so,
            float* __restrict__ psum, float* __restrict__ psq) {
    constexpr int MI = BM / 32;                      // M-frags per wave (4 or 2); also A-chunks
    __shared__ __align__(16) _Float16 Als[BM * 64];
    __shared__ __align__(16) _Float16 Bls[128 * 64];
    const int tid = threadIdx.x, lane = tid & 63, w = tid >> 6;
    int bsw, lsw;
    swz_batch(blockIdx.x, bsw, lsw);                 // lsw in [0, 2048/BM)
    constexpr int TPB = 2048 / BM;                   // M-tiles per batch
    const int m0 = (bsw * TPB + lsw) * BM;
    const int n0 = blockIdx.y * 128;
    const int wr = (w >> 1) * (BM / 2), wc = (w & 1) * 64;

    f32x4 acc[MI][4];
#pragma unroll
    for (int i = 0; i < MI; ++i)
#pragma unroll
        for (int j = 0; j < 4; ++j) acc[i][j] = (f32x4){0.f, 0.f, 0.f, 0.f};

    // B staging map: 4 chunks/thread covering 128 rows x 64 cols
    int srb[4], scb[4];
#pragma unroll
    for (int j = 0; j < 4; ++j) {
        int idx = w * 256 + j * 64 + lane;
        srb[j] = idx >> 3;
        scb[j] = ((idx & 7) ^ (srb[j] & 7)) * 8;
    }
    // A staging map: MI chunks/thread covering BM rows x 64 cols
    int sra[MI], sca[MI];
#pragma unroll
    for (int j = 0; j < MI; ++j) {
        int idx = w * (MI * 64) + j * 64 + lane;
        sra[j] = idx >> 3;
        sca[j] = ((idx & 7) ^ (sra[j] & 7)) * 8;
    }
    int aoff[MI][2], boff[4][2];
#pragma unroll
    for (int i = 0; i < MI; ++i) {
        int ra = wr + i * 16 + (lane & 15);
#pragma unroll
        for (int t = 0; t < 2; ++t)
            aoff[i][t] = ra * 64 + ((((lane >> 4) + t * 4) ^ (ra & 7)) * 8);
    }
#pragma unroll
    for (int j = 0; j < 4; ++j) {
        int rb = wc + j * 16 + (lane & 15);
#pragma unroll
        for (int t = 0; t < 2; ++t)
            boff[j][t] = rb * 64 + ((((lane >> 4) + t * 4) ^ (rb & 7)) * 8);
    }

    for (int c0 = 0; c0 < K; c0 += 64) {
#pragma unroll
        for (int j = 0; j < MI; ++j) {
            const _Float16* ga = &A[(size_t)(m0 + sra[j]) * sa + c0 + sca[j]];
            __builtin_amdgcn_global_load_lds((gas_t)(const void*)ga,
                                             (las_t)(void*)&Als[(w * MI * 64 + j * 64) * 8], 16, 0, 0);
        }
#pragma unroll
        for (int j = 0; j < 4; ++j) {
            const _Float16* gb = &Bw[(size_t)(n0 + srb[j]) * K + c0 + scb[j]];
            __builtin_amdgcn_global_load_lds((gas_t)(const void*)gb,
                                             (las_t)(void*)&Bls[(w * 256 + j * 64) * 8], 16, 0, 0);
        }
        __syncthreads();
#pragma unroll
        for (int t = 0; t < 2; ++t) {
            half8v a[MI], b[4];
#pragma unroll
            for (int i = 0; i < MI; ++i) a[i] = *(const half8v*)&Als[aoff[i][t]];
#pragma unroll
            for (int j = 0; j < 4; ++j) b[j] = *(const half8v*)&Bls[boff[j][t]];
#pragma unroll
            for (int i = 0; i < MI; ++i)
#pragma unroll
                for (int j = 0; j < 4; ++j)
                    acc[i][j] = __builtin_amdgcn_mfma_f32_16x16x32_f16(a[i], b[j], acc[i][j], 0, 0, 0);
        }
        __syncthreads();
    }
#pragma unroll
    for (int i = 0; i < MI; ++i)
#pragma unroll
        for (int j = 0; j < 4; ++j)
#pragma unroll
            for (int e = 0; e < 4; ++e) {
                int row = m0 + wr + i * 16 + (lane >> 4) * 4 + e;
                int col = n0 + wc + j * 16 + (lane & 15);
                outp[(size_t)row * so + col] = (_Float16)acc[i][j][e];
            }
    if constexpr (STATS) {
        int slice = blockIdx.x & 63;
#pragma unroll
        for (int j = 0; j < 4; ++j) {
            float s = 0.f, q = 0.f;
#pragma unroll
            for (int i = 0; i < MI; ++i)
#pragma unroll
                for (int e = 0; e < 4; ++e) {
                    float v = acc[i][j][e];
                    s += v; q += v * v;
                }
            s += __shfl_xor(s, 16); s += __shfl_xor(s, 32);
            q += __shfl_xor(q, 16); q += __shfl_xor(q, 32);
            if ((lane >> 4) == 0) {
                int col = n0 + wc + j * 16 + lane;
                atomicAdd(&psum[slice * 1024 + col], s);
                atomicAdd(&psq[slice * 1024 + col], q);
            }
        }
    }
}

// ---------------- layer-0: fused dense (C=3) + gather-reduce + BN stats ----------------
__global__ __launch_bounds__(256)
void k_gather0(const float* __restrict__ x, const float* __restrict__ w0,
               const int* __restrict__ nidx, const float* __restrict__ g,
               _Float16* __restrict__ exth,
               float* __restrict__ psum, float* __restrict__ psq) {
    constexpr int O = 64, VPT = 8, P = 32;
    __shared__ float s_red[P * O];
    __shared__ float q_red[P * O];
    const int tid = threadIdx.x;
    const int pl = tid / VPT, v = tid % VPT;
    int bsw, local;
    swz_batch(blockIdx.x, bsw, local);               // grid 256: local in [0,32)
    const int bbase = bsw * N_;
    const int p = bbase + local * P + pl;
    float wa[8][3], wd[8][3], sg[8];
#pragma unroll
    for (int e = 0; e < 8; ++e) {
        int o = v * 8 + e;
        float a0 = w0[o * 6], a1 = w0[o * 6 + 1], a2 = w0[o * 6 + 2];
        wa[e][0] = a0; wa[e][1] = a1; wa[e][2] = a2;
        wd[e][0] = w0[o * 6 + 3] - a0;
        wd[e][1] = w0[o * 6 + 4] - a1;
        wd[e][2] = w0[o * 6 + 5] - a2;
        sg[e] = (g[o] >= 0.f) ? 1.f : -1.f;
    }
    float mx[8], sm[8], sq[8];
#pragma unroll
    for (int e = 0; e < 8; ++e) { mx[e] = -3.4e38f; sm[e] = 0.f; sq[e] = 0.f; }
    const int* np = nidx + p * K_;
#pragma unroll 4
    for (int k = 0; k < K_; ++k) {
        int j = bbase + np[k];
        float x0 = x[j * 3], x1 = x[j * 3 + 1], x2 = x[j * 3 + 2];
#pragma unroll
        for (int e = 0; e < 8; ++e) {
            float f = wa[e][0] * x0 + wa[e][1] * x1 + wa[e][2] * x2;
            mx[e] = fmaxf(mx[e], f * sg[e]);
            sm[e] += f;
            sq[e] += f * f;
        }
    }
    float xp0 = x[p * 3], xp1 = x[p * 3 + 1], xp2 = x[p * 3 + 2];
    const float Kf = (float)K_;
    half8v exo;
#pragma unroll
    for (int e = 0; e < 8; ++e) {
        float zf = wd[e][0] * xp0 + wd[e][1] * xp1 + wd[e][2] * xp2;
        exo[e] = (_Float16)(sg[e] * mx[e] + zf);
        s_red[pl * O + v * 8 + e] = sm[e] + Kf * zf;
        q_red[pl * O + v * 8 + e] = sq[e] + 2.f * zf * sm[e] + Kf * zf * zf;
    }
    *(half8v*)&exth[(size_t)p * O + v * 8] = exo;
    __syncthreads();
    int slice = blockIdx.x & 63;
    for (int ch = tid; ch < O; ch += 256) {
        float s = 0.f, q = 0.f;
#pragma unroll
        for (int pp = 0; pp < P; ++pp) { s += s_red[pp * O + ch]; q += q_red[pp * O + ch]; }
        atomicAdd(&psum[slice * 1024 + ch], s);
        atomicAdd(&psq[slice * 1024 + ch], q);
    }
}

// ---------------- gather-reduce + fused BN stats (single extremum, batch-XCD-swizzled) ----------------
template<int O>
__global__ __launch_bounds__(256)
void k_gather(const _Float16* __restrict__ Z, const int* __restrict__ nidx,
              const float* __restrict__ g,
              _Float16* __restrict__ exth,
              float* __restrict__ psum, float* __restrict__ psq) {
    constexpr int VPT = O / 8, P = 256 / VPT;
    __shared__ float s_red[P * O];
    __shared__ float q_red[P * O];
    const int tid = threadIdx.x;
    const int pl = tid / VPT, v = tid % VPT;
    int bsw, local;
    swz_batch(blockIdx.x, bsw, local);               // local in [0, 2048/P)
    const int bbase = bsw * N_;
    const int p = bbase + local * P + pl;
    float sg[8];
#pragma unroll
    for (int e = 0; e < 8; ++e) sg[e] = (g[v * 8 + e] >= 0.f) ? 1.f : -1.f;
    float mx[8], sm[8], sq[8];
#pragma unroll
    for (int e = 0; e < 8; ++e) { mx[e] = -3.4e38f; sm[e] = 0.f; sq[e] = 0.f; }
    const int* np = nidx + p * K_;
#pragma unroll 4
    for (int k = 0; k < K_; ++k) {
        int j = np[k];
        half8v z = *(const half8v*)&Z[(size_t)(bbase + j) * (2 * O) + v * 8];
#pragma unroll
        for (int e = 0; e < 8; ++e) {
            float f = (float)z[e];
            mx[e] = fmaxf(mx[e], f * sg[e]);
            sm[e] += f;
            sq[e] += f * f;
        }
    }
    half8v zd = *(const half8v*)&Z[(size_t)p * (2 * O) + O + v * 8];
    const float Kf = (float)K_;
    half8v exo;
#pragma unroll
    for (int e = 0; e < 8; ++e) {
        float zf = (float)zd[e];
        exo[e] = (_Float16)(sg[e] * mx[e] + zf);
        s_red[pl * O + v * 8 + e] = sm[e] + Kf * zf;
        q_red[pl * O + v * 8 + e] = sq[e] + 2.f * zf * sm[e] + Kf * zf * zf;
    }
    *(half8v*)&exth[(size_t)p * O + v * 8] = exo;
    __syncthreads();
    int slice = blockIdx.x & 63;
    for (int ch = tid; ch < O; ch += 256) {
        float s = 0.f, q = 0.f;
#pragma unroll
        for (int pp = 0; pp < P; ++pp) { s += s_red[pp * O + ch]; q += q_red[pp * O + ch]; }
        atomicAdd(&psum[slice * 1024 + ch], s);
        atomicAdd(&psq[slice * 1024 + ch], q);
    }
}

// ---------------- finalize: sum 64 slices -> scale/shift ----------------
__global__ void k_finalize_sl(const float* __restrict__ psum, const float* __restrict__ psq,
                              const float* __restrict__ g, const float* __restrict__ b,
                              float cntInv, int O,
                              float* __restrict__ scale, float* __restrict__ shift) {
    int o = blockIdx.x * 256 + threadIdx.x;
    if (o >= O) return;
    float s = 0.f, q = 0.f;
    for (int i = 0; i < 64; ++i) { s += psum[i * 1024 + o]; q += psq[i * 1024 + o]; }
    float m = s * cntInv;
    float v = q * cntInv - m * m;
    float sc = g[o] * rsqrtf(fmaxf(v, 0.f) + EPSBN);
    scale[o] = sc;
    shift[o] = b[o] - m * sc;
}

// BN + lrelu on selected extremum (fp16 in) -> fp16 cat slice; batch-XCD-swizzled
template<int O>
__global__ void k_bn_apply(const _Float16* __restrict__ exth,
                           const float* __restrict__ scale, const float* __restrict__ shift,
                           _Float16* __restrict__ cath, int coff) {
    constexpr int PPB = 2048 / O;                    // points per block (256 thr x 8 elems)
    int bsw, local;
    swz_batch(blockIdx.x, bsw, local);
    const int pt_base = bsw * N_ + local * PPB;
    int tid = threadIdx.x;
    int pt = pt_base + (tid * 8) / O;
    int v8 = (tid * 8) & (O - 1);
    half8v hx = *(const half8v*)&exth[(size_t)pt * O + v8];
    half8v r;
#pragma unroll
    for (int e = 0; e < 8; ++e) {
        int o = v8 + e;
        float y = scale[o] * (float)hx[e] + shift[o];
        y = y > 0.f ? y : 0.2f * y;
        r[e] = (_Float16)y;
    }
    *(half8v*)&cath[(size_t)pt * 960 + coff + v8] = r;
}

// BN+lrelu on Y4 (B,N,1024 fp16), transposed store -> fo (B,1024,N f32), fused pool partials
__global__ void k_feats_out(const _Float16* __restrict__ Y4, const float* __restrict__ scale,
                            const float* __restrict__ shift, float* __restrict__ fo,
                            float* __restrict__ pmax, float* __restrict__ psumn) {
    __shared__ float tile[32][33];
    int tx = threadIdx.x, ty = threadIdx.y;      // (32,8)
    int b = blockIdx.z;
    int n0 = blockIdx.x * 32, c0 = blockIdx.y * 32;
#pragma unroll
    for (int i = 0; i < 4; ++i) {
        int n = n0 + ty + i * 8;
        int c = c0 + tx;
        float v = (float)Y4[((size_t)(b * N_ + n)) * 1024 + c];
        v = scale[c] * v + shift[c];
        v = v > 0.f ? v : 0.2f * v;
        tile[ty + i * 8][tx] = v;
    }
    __syncthreads();
#pragma unroll
    for (int i = 0; i < 4; ++i) {
        int c = c0 + ty + i * 8;
        int n = n0 + tx;
        float v2 = tile[tx][ty + i * 8];
        fo[((size_t)(b * 1024 + c)) * N_ + n] = v2;
        float mx = v2, s = v2;
#pragma unroll
        for (int d = 1; d < 32; d <<= 1) {
            mx = fmaxf(mx, __shfl_xor(mx, d));
            s += __shfl_xor(s, d);
        }
        if (tx == 0) {
            int bc = (b << 10) + c;
            pmax[(size_t)bc * 64 + blockIdx.x] = mx;
            psumn[(size_t)bc * 64 + blockIdx.x] = s;
        }
    }
}

// final pool: per (b,c) reduce 64 tile-partials -> z0 (B,2048) = [max | mean]
__global__ void k_pool2(const float* __restrict__ pmax, const float* __restrict__ psumn,
                        float* __restrict__ z0) {
    int bc = blockIdx.x * 4 + (threadIdx.x >> 6);
    int lane = threadIdx.x & 63;
    float mx = pmax[(size_t)bc * 64 + lane];
    float s  = psumn[(size_t)bc * 64 + lane];
#pragma unroll
    for (int d = 1; d < 64; d <<= 1) {
        mx = fmaxf(mx, __shfl_xor(mx, d));
        s += __shfl_xor(s, d);
    }
    if (lane == 0) {
        int b = bc >> 10, c = bc & 1023;
        z0[b * 2048 + c] = mx;
        z0[b * 2048 + 1024 + c] = s * (1.f / N_);
    }
}

// ---------------- FC: one wave per (batch, output) dot product; optional fused batch-BN+lrelu ----------------
__global__ void k_fc(const float* __restrict__ zin, const float* __restrict__ W,
                     const float* __restrict__ bias,
                     const float* __restrict__ gg, const float* __restrict__ gb,
                     int C, int O, float* __restrict__ zout) {
    __shared__ float sh4[4];
    const int b = threadIdx.x >> 6;
    const int lane = threadIdx.x & 63;
    const int o = blockIdx.x;
    const float* wr = W + (size_t)o * C;
    const float* zr = zin + b * C;
    float s = 0.f;
    for (int c = lane * 4; c < C; c += 256) {
        const float4 wv = *(const float4*)&wr[c];
        const float4 zv = *(const float4*)&zr[c];
        s += wv.x * zv.x + wv.y * zv.y + wv.z * zv.z + wv.w * zv.w;
    }
    s += __shfl_xor(s, 1);
    s += __shfl_xor(s, 2);
    s += __shfl_xor(s, 4);
    s += __shfl_xor(s, 8);
    s += __shfl_xor(s, 16);
    s += __shfl_xor(s, 32);
    if (!gg) {
        if (lane == 0) zout[b * O + o] = s + (bias ? bias[o] : 0.f);
        return;
    }
    if (lane == 0) sh4[b] = s + (bias ? bias[o] : 0.f);
    __syncthreads();
    if (threadIdx.x == 0) {
        float v0 = sh4[0], v1 = sh4[1], v2 = sh4[2], v3 = sh4[3];
        float m = 0.25f * (v0 + v1 + v2 + v3);
        float d0 = v0 - m, d1 = v1 - m, d2 = v2 - m, d3 = v3 - m;
        float var = 0.25f * (d0 * d0 + d1 * d1 + d2 * d2 + d3 * d3);
        float sc = gg[o] * rsqrtf(var + EPSBN);
        float shv = gb[o];
        float r0 = sc * d0 + shv, r1 = sc * d1 + shv, r2 = sc * d2 + shv, r3 = sc * d3 + shv;
        zout[o]         = r0 > 0.f ? r0 : 0.2f * r0;
        zout[O + o]     = r1 > 0.f ? r1 : 0.2f * r1;
        zout[2 * O + o] = r2 > 0.f ? r2 : 0.2f * r2;
        zout[3 * O + o] = r3 > 0.f ? r3 : 0.2f * r3;
    }
}

// ---------------- launch ----------------

extern "C" void kernel_launch(void* const* d_in, const int* in_sizes, int n_in,
                              void* d_out, int out_size, void* d_ws, size_t ws_size,
                              hipStream_t stream) {
    const float* x    = (const float*)d_in[0];
    const int*   nidx = (const int*)d_in[1];
    const float* w[5]  = {(const float*)d_in[2], (const float*)d_in[5], (const float*)d_in[8],
                          (const float*)d_in[11], (const float*)d_in[14]};
    const float* g[5]  = {(const float*)d_in[3], (const float*)d_in[6], (const float*)d_in[9],
                          (const float*)d_in[12], (const float*)d_in[15]};
    const float* bb[5] = {(const float*)d_in[4], (const float*)d_in[7], (const float*)d_in[10],
                          (const float*)d_in[13], (const float*)d_in[16]};
    const float* lw1 = (const float*)d_in[17];
    const float* g6  = (const float*)d_in[18];
    const float* b6  = (const float*)d_in[19];
    const float* lw2 = (const float*)d_in[20];
    const float* lb2 = (const float*)d_in[21];
    const float* g7  = (const float*)d_in[22];
    const float* b7  = (const float*)d_in[23];
    const float* lw3 = (const float*)d_in[24];
    const float* lb3 = (const float*)d_in[25];

    float* out = (float*)d_out;
    float* fo  = out + 1024;              // feats (B,1024,N)

    uint8_t* base8 = (uint8_t*)d_ws;
    size_t off = 0;
    auto alloc = [&](size_t bytes) -> void* {
        void* r = base8 + off;
        off += (bytes + 255) & ~(size_t)255;
        return r;
    };
    _Float16* cath = (_Float16*)alloc((size_t)B_ * N_ * 960 * 2);   // 15.7 MB
    _Float16* Z    = (_Float16*)alloc((size_t)8192 * 1024 * 2);     // 16.8 MB
    _Float16* exth = (_Float16*)alloc((size_t)8192 * 512 * 2);      // 8.4 MB
    _Float16* Y4   = (_Float16*)alloc((size_t)8192 * 1024 * 2);     // 16.8 MB
    _Float16* W2h1 = (_Float16*)alloc((size_t)256 * 64 * 2);
    _Float16* W2h2 = (_Float16*)alloc((size_t)512 * 128 * 2);
    _Float16* W2h3 = (_Float16*)alloc((size_t)1024 * 256 * 2);
    _Float16* w4h  = (_Float16*)alloc((size_t)1024 * 960 * 2);
    float* psumall = (float*)alloc((size_t)5 * 131072 * 4);         // 2.6 MB, 5 regions
    float* pmax  = (float*)alloc((size_t)4096 * 64 * 4);            // 1 MB
    float* psumn = (float*)alloc((size_t)4096 * 64 * 4);            // 1 MB
    float* scalev= (float*)alloc(1024 * 4);
    float* shiftv= (float*)alloc(1024 * 4);
    float* z0    = (float*)alloc(8192 * 4);
    float* z1    = (float*)alloc(4096 * 4);
    float* z2    = (float*)alloc(2048 * 4);
    (void)ws_size; (void)in_sizes; (void)n_in; (void)out_size;

    auto psumR = [&](int r) { return psumall + (size_t)r * 131072; };
    auto psqR  = [&](int r) { return psumall + (size_t)r * 131072 + 65536; };

    // one upfront zero of all stat regions + one fused weight-prep launch
    hipMemsetAsync(psumall, 0, (size_t)5 * 131072 * 4, stream);
    k_prep_all<<<(8192 + 32768 + 131072 + 983040 + 255) / 256, 256, 0, stream>>>(
        w[1], w[2], w[3], w[4], W2h1, W2h2, W2h3, w4h);

    // ---- layer 0 (C=3 -> O=64): fused dense + gather (no Z0 round-trip) ----
    k_gather0<<<256, 256, 0, stream>>>(x, w[0], nidx, g[0], exth, psumR(0), psqR(0));
    k_finalize_sl<<<1, 256, 0, stream>>>(psumR(0), psqR(0), g[0], bb[0], 1.f / (B_ * N_ * K_),
                                         64, scalev, shiftv);
    k_bn_apply<64><<<256, 256, 0, stream>>>(exth, scalev, shiftv, cath, 0);

    // ---- layers 1-3: dense MFMA GEMM + fused gather ----
    // G1 uses BM=64 (grid 128x2=256 blocks = full CU coverage); G2-G4 keep BM=128.
    k_gemm<false, 64><<<dim3(128, 2), 256, 0, stream>>>(cath + 0, 960, W2h1, 64,
                                                        Z, 256, nullptr, nullptr);
    k_gather<128><<<512, 256, 0, stream>>>(Z, nidx, g[1], exth, psumR(1), psqR(1));
    k_finalize_sl<<<1, 256, 0, stream>>>(psumR(1), psqR(1), g[1], bb[1],
                                         1.f / (B_ * N_ * K_), 128, scalev, shiftv);
    k_bn_apply<128><<<512, 256, 0, stream>>>(exth, scalev, shiftv, cath, 64);

    k_gemm<false, 128><<<dim3(64, 4), 256, 0, stream>>>(cath + 64, 960, W2h2, 128,
                                                        Z, 512, nullptr, nullptr);
    k_gather<256><<<1024, 256, 0, stream>>>(Z, nidx, g[2], exth, psumR(2), psqR(2));
    k_finalize_sl<<<1, 256, 0, stream>>>(psumR(2), psqR(2), g[2], bb[2],
                                         1.f / (B_ * N_ * K_), 256, scalev, shiftv);
    k_bn_apply<256><<<1024, 256, 0, stream>>>(exth, scalev, shiftv, cath, 192);

    k_gemm<false, 128><<<dim3(64, 8), 256, 0, stream>>>(cath + 192, 960, W2h3, 256,
                                                        Z, 1024, nullptr, nullptr);
    k_gather<512><<<2048, 256, 0, stream>>>(Z, nidx, g[3], exth, psumR(3), psqR(3));
    k_finalize_sl<<<2, 256, 0, stream>>>(psumR(3), psqR(3), g[3], bb[3],
                                         1.f / (B_ * N_ * K_), 512, scalev, shiftv);
    k_bn_apply<512><<<2048, 256, 0, stream>>>(exth, scalev, shiftv, cath, 448);

    // ---- feats = lrelu(bn(w4 @ cat)) with fused column stats ----
    k_gemm<true, 128><<<dim3(64, 8), 256, 0, stream>>>(cath, 960, w4h, 960, Y4, 1024,
                                                       psumR(4), psqR(4));
    k_finalize_sl<<<4, 256, 0, stream>>>(psumR(4), psqR(4), g[4], bb[4], 1.f / (B_ * N_), 1024,
                                         scalev, shiftv);
    k_feats_out<<<dim3(64, 32, 4), dim3(32, 8), 0, stream>>>(Y4, scalev, shiftv, fo, pmax, psumn);
    k_pool2<<<1024, 256, 0, stream>>>(pmax, psumn, z0);

    // ---- FC head (BN fused into FC blocks) ----
    k_fc<<<1024, 256, 0, stream>>>(z0, lw1, nullptr, g6, b6, 2048, 1024, z1);
    k_fc<<<512, 256, 0, stream>>>(z1, lw2, lb2, g7, b7, 1024, 512, z2);
    k_fc<<<256, 256, 0, stream>>>(z2, lw3, lb3, nullptr, nullptr, 512, 256, out);
}